// Round 4
// baseline (692.880 us; speedup 1.0000x reference)
//
#include <hip/hip_runtime.h>

typedef unsigned short u16;
typedef unsigned int u32;
typedef __bf16 bf16x8 __attribute__((ext_vector_type(8)));
typedef float f32x4 __attribute__((ext_vector_type(4)));

#define BB   2
#define SS   2048
#define EE   2048
#define HH   2688
#define NHH  4
#define DHH  672
#define NPHH 672
#define H2   5376
#define H3   8064

__device__ __forceinline__ float b2f(u16 u) {
  union { unsigned int i; float f; } c; c.i = ((unsigned int)u) << 16; return c.f;
}
__device__ __forceinline__ u16 f2b(float f) {
  union { float f; unsigned int i; } c; c.f = f;
  unsigned int i = c.i;
  return (u16)((i + 0x7FFFu + ((i >> 16) & 1u)) >> 16);
}
__device__ __forceinline__ float silu_f(float x) { return x / (1.f + __expf(-x)); }
__device__ __forceinline__ float logsig_f(float f) {
  return (f >= 0.f) ? -log1pf(__expf(-f)) : (f - log1pf(__expf(f)));
}

// async global->LDS, 16B per lane; dst wave-uniform base, HW adds lane*16B
__device__ __forceinline__ void gl2lds16(const u16* g, u16* s) {
  __builtin_amdgcn_global_load_lds(
      (const __attribute__((address_space(1))) u32*)g,
      (__attribute__((address_space(3))) u32*)s, 16, 0, 0);
}

template <int N> __device__ __forceinline__ void vmwait() {
  asm volatile("s_waitcnt vmcnt(%0)" :: "n"(N) : "memory");
}

// ---------------------------------------------------------------------------
// gemm256: faithful m201-template NT GEMM (bf16): C[i,j] = sum_k A[i,k]*Bt[j,k]
// 256x256 tile, BK=64, 8 waves (2M x 4N), wave-tile 128x64, LDS = 2 x 64 KiB
// double buffer (A 256x64 | B 256x64 per buffer). 4 phases per K-tile:
//   ph p: { ds_read A-frags 2p,2p+1 (4 b128; ph0 also all 8 B-frags, held in
//           regs) | stage ONE tensor-half (2 gl2lds) | s_barrier | lgkmcnt(0)
//           | setprio(1) 16 MFMA (C-quadrant x K=64) setprio(0) | s_barrier }
// Stage schedule (WAR-safe): during tile t: ph0/ph1 stage (t+1).Ah0/Ah1 into
// buf[t+1 & 1] (dead region); ph2/ph3 stage (t+2).Bh0/Bh1 into buf[t & 1]
// (B dead after ph0's lgkm). Tile boundary: vmcnt(4) (drains old (t+1).B +
// (t+1).A, leaves (t+2).B in flight) -- counted, never 0 mid-loop.
// Bank swizzle: 16B-chunk XOR involution chunk ^= (row&7) on BOTH the
// pre-swizzled global source and the ds_read address (0 conflicts in r2/r3).
// MODE 0 plain; MODE 1 QK diag-skip; MODE 2 PV (row scale, causal K-cap).
// Requires: M % 256 == 0, K % 64 == 0. N masked on store; B staging may
// over-read up to 255 rows past N (callers guarantee in-bounds memory).
// ---------------------------------------------------------------------------
template <int MODE, int OUTF32>
__global__ __launch_bounds__(512, 1) void gemm256(
    const u16* __restrict__ A, const u16* __restrict__ Bt, void* __restrict__ Cp,
    int M, int N, int K, int lda, int ldb, int ldc,
    long sAhi, long sAlo, long sBhi, long sBlo, long sChi, long sClo,
    const float* __restrict__ aux1, const float* __restrict__ aux2,
    int auxStride, int causal)
{
  __shared__ __align__(16) u16 sm[2 * 32768];   // 128 KiB

  // bijective XCD-aware block swizzle
  int gx = gridDim.x;
  int nwg = gx * gridDim.y;
  int flat = blockIdx.y * gx + blockIdx.x;
  int qq = nwg >> 3, r8 = nwg & 7;
  int xcd = flat & 7, seq = flat >> 3;
  int logical = (xcd < r8 ? xcd * (qq + 1) : r8 * (qq + 1) + (xcd - r8) * qq) + seq;
  int bx = logical % gx, by = logical / gx;
  int m0 = by * 256, n0 = bx * 256;
  if (MODE == 1 && n0 > m0 + 255) return;

  int bz = blockIdx.z, bzh = bz >> 2, bzl = bz & 3;
  A  += bzh * sAhi + bzl * sAlo;
  Bt += bzh * sBhi + bzl * sBlo;
  const float* a1 = aux1 ? aux1 + (long)bz * auxStride : nullptr;
  const float* a2 = aux2 ? aux2 + (long)bz * auxStride : nullptr;
  u16*   C16 = (u16*)Cp + bzh * sChi + bzl * sClo;
  float* C32 = (float*)Cp + bzh * sChi + bzl * sClo;

  int t = threadIdx.x, lane = t & 63, w = t >> 6;
  int l15 = lane & 15, quad = lane >> 4;
  int wr = w >> 2, wc = w & 3;        // wave -> (M half, N quarter)
  int cx = l15 & 7;                   // row&7 for frag rows (bases are x16)

  // staging: thread t covers (row = t>>3 in a 64-row group, chunk16 = t&7);
  // pre-swizzled source col: chunk ^ (row & 7)
  int srow = t >> 3;
  int sw8 = ((t & 7) ^ (srow & 7)) * 8;
  const u16* pA = A + (long)(m0 + srow) * lda + sw8;
  const u16* pB = Bt + (long)(n0 + srow) * ldb + sw8;

  f32x4 acc[8][4];
#pragma unroll
  for (int i = 0; i < 8; i++)
#pragma unroll
    for (int j = 0; j < 4; j++) acc[i][j] = (f32x4){0.f, 0.f, 0.f, 0.f};

  int Keff = (MODE == 2 && causal) ? min(K, m0 + 256) : K;
  int T = Keff >> 6;

  // stage one tensor-half (128 rows x 64 cols) = 2 gl2lds per thread
  auto SA = [&](int buf, int h, int tt) {
    int k2 = tt << 6;
    u16* d = sm + buf * 32768 + h * 8192 + w * 512;
    gl2lds16(pA + (long)(h * 128) * lda + k2, d);
    gl2lds16(pA + (long)(h * 128 + 64) * lda + k2, d + 4096);
  };
  auto SB = [&](int buf, int h, int tt) {
    int k2 = tt << 6;
    u16* d = sm + buf * 32768 + 16384 + h * 8192 + w * 512;
    gl2lds16(pB + (long)(h * 128) * ldb + k2, d);
    gl2lds16(pB + (long)(h * 128 + 64) * ldb + k2, d + 4096);
  };

  // prologue: tile0 fully (8 loads) + tile1's B halves (4) -> vmcnt(4)
  SA(0, 0, 0); SA(0, 1, 0); SB(0, 0, 0); SB(0, 1, 0);
  if (T > 1) { SB(1, 0, 1); SB(1, 1, 1); vmwait<4>(); }
  else vmwait<0>();
  __builtin_amdgcn_s_barrier();
  __builtin_amdgcn_sched_barrier(0);

  for (int tq = 0; tq < T; ++tq) {
    u16* Sb = sm + (tq & 1) * 32768;
    int nb = (tq + 1) & 1;
    bf16x8 bfr[4][2];

#pragma unroll
    for (int p = 0; p < 4; ++p) {
      // ds reads for this phase
      bf16x8 a0, a1v;
      a0  = *reinterpret_cast<const bf16x8*>(
          Sb + (wr * 128 + (2 * p) * 16 + l15) * 64 + ((quad ^ cx) << 3));
      a1v = *reinterpret_cast<const bf16x8*>(
          Sb + (wr * 128 + (2 * p + 1) * 16 + l15) * 64 + ((quad ^ cx) << 3));
      bf16x8 a0h, a1h;
      a0h = *reinterpret_cast<const bf16x8*>(
          Sb + (wr * 128 + (2 * p) * 16 + l15) * 64 + (((4 + quad) ^ cx) << 3));
      a1h = *reinterpret_cast<const bf16x8*>(
          Sb + (wr * 128 + (2 * p + 1) * 16 + l15) * 64 + (((4 + quad) ^ cx) << 3));
      if (p == 0) {
#pragma unroll
        for (int j = 0; j < 4; ++j) {
          bfr[j][0] = *reinterpret_cast<const bf16x8*>(
              Sb + 16384 + (wc * 64 + j * 16 + l15) * 64 + ((quad ^ cx) << 3));
          bfr[j][1] = *reinterpret_cast<const bf16x8*>(
              Sb + 16384 + (wc * 64 + j * 16 + l15) * 64 + (((4 + quad) ^ cx) << 3));
        }
      }
      // stage schedule: ph0/ph1 -> (t+1).A halves; ph2/ph3 -> (t+2).B halves
      if (p == 0) { if (tq + 1 < T) SA(nb, 0, tq + 1); }
      else if (p == 1) { if (tq + 1 < T) SA(nb, 1, tq + 1); }
      else if (p == 2) { if (tq + 2 < T) SB(tq & 1, 0, tq + 2); }
      else { if (tq + 2 < T) SB(tq & 1, 1, tq + 2); }

      __builtin_amdgcn_s_barrier();
      asm volatile("s_waitcnt lgkmcnt(0)" ::: "memory");
      __builtin_amdgcn_sched_barrier(0);
      __builtin_amdgcn_s_setprio(1);
#pragma unroll
      for (int j = 0; j < 4; ++j) {
        acc[2 * p][j] = __builtin_amdgcn_mfma_f32_16x16x32_bf16(a0, bfr[j][0], acc[2 * p][j], 0, 0, 0);
        acc[2 * p][j] = __builtin_amdgcn_mfma_f32_16x16x32_bf16(a0h, bfr[j][1], acc[2 * p][j], 0, 0, 0);
        acc[2 * p + 1][j] = __builtin_amdgcn_mfma_f32_16x16x32_bf16(a1v, bfr[j][0], acc[2 * p + 1][j], 0, 0, 0);
        acc[2 * p + 1][j] = __builtin_amdgcn_mfma_f32_16x16x32_bf16(a1h, bfr[j][1], acc[2 * p + 1][j], 0, 0, 0);
      }
      __builtin_amdgcn_s_setprio(0);
      __builtin_amdgcn_sched_barrier(0);
      __builtin_amdgcn_s_barrier();
    }
    // tile boundary: (t+1) must be fully resident; keep (t+2).B in flight
    if (tq + 1 < T) {
      if (tq + 2 < T) vmwait<4>(); else vmwait<0>();
      __builtin_amdgcn_s_barrier();
      __builtin_amdgcn_sched_barrier(0);
    }
  }

  const float rs = 0.03857583749f;  // 1/sqrt(672)
#pragma unroll
  for (int i = 0; i < 8; i++) {
#pragma unroll
    for (int j = 0; j < 4; j++) {
      int col = n0 + wc * 64 + j * 16 + l15;
      if (col >= N) continue;
#pragma unroll
      for (int rr = 0; rr < 4; rr++) {
        int row = m0 + wr * 128 + i * 16 + quad * 4 + rr;
        if (row >= M) continue;
        float v = acc[i][j][rr];
        if (MODE == 1) v = (col <= row) ? v * rs * __expf(a1[col] - a2[row]) : 0.f;
        else if (MODE == 2) v = v * a1[row];
        if (OUTF32) C32[(long)row * ldc + col] = v;
        else        C16[(long)row * ldc + col] = f2b(v);
      }
    }
  }
}

// ---------------------------------------------------------------------------
// gemm8: 2-phase NT GEMM (bf16), BK=64, 128x256 tile, ring-3, lead-2.
// Kept for gates / PV / out-proj.
// ---------------------------------------------------------------------------
template <int MODE, int OUTF32>
__global__ __launch_bounds__(512, 1) void gemm8(
    const u16* __restrict__ A, const u16* __restrict__ Bt, void* __restrict__ Cp,
    int M, int N, int K, int lda, int ldb, int ldc,
    long sAhi, long sAlo, long sBhi, long sBlo, long sChi, long sClo,
    const float* __restrict__ aux1, const float* __restrict__ aux2,
    int auxStride, int causal)
{
  constexpr int SLOT = (128 + 256) * 64;   // u16 per ring slot (48 KiB)
  __shared__ __align__(16) u16 sm[3 * SLOT];  // 144 KiB

  int gx = gridDim.x;
  int nwg = gx * gridDim.y;
  int flat = blockIdx.y * gx + blockIdx.x;
  int qq = nwg >> 3, r8 = nwg & 7;
  int xcd = flat & 7, seq = flat >> 3;
  int logical = (xcd < r8 ? xcd * (qq + 1) : r8 * (qq + 1) + (xcd - r8) * qq) + seq;
  int bx = logical % gx, by = logical / gx;
  int m0 = by * 128, n0 = bx * 256;
  if (MODE == 1 && n0 > m0 + 127) return;

  int bz = blockIdx.z, bzh = bz >> 2, bzl = bz & 3;
  A  += bzh * sAhi + bzl * sAlo;
  Bt += bzh * sBhi + bzl * sBlo;
  const float* a1 = aux1 ? aux1 + (long)bz * auxStride : nullptr;
  const float* a2 = aux2 ? aux2 + (long)bz * auxStride : nullptr;
  u16*   C16 = (u16*)Cp + bzh * sChi + bzl * sClo;
  float* C32 = (float*)Cp + bzh * sChi + bzl * sClo;

  int t = threadIdx.x, lane = t & 63, w = t >> 6;
  int l15 = lane & 15, quad = lane >> 4;
  int wr = w >> 2, wc = w & 3;

  int srow = t >> 3;
  int sw8 = ((t & 7) ^ (srow & 7)) * 8;
  const u16* pS[6];
  int dOf[6];
#pragma unroll
  for (int c = 0; c < 2; ++c) {
    pS[c] = A + (long)(m0 + c * 64 + srow) * lda + sw8;
    dOf[c] = c * 4096 + w * 512;
  }
#pragma unroll
  for (int c = 0; c < 4; ++c) {
    pS[2 + c] = Bt + (long)(n0 + c * 64 + srow) * ldb + sw8;
    dOf[2 + c] = 8192 + c * 4096 + w * 512;
  }

  f32x4 acc[4][4];
#pragma unroll
  for (int i = 0; i < 4; i++)
#pragma unroll
    for (int j = 0; j < 4; j++) acc[i][j] = (f32x4){0.f, 0.f, 0.f, 0.f};

  int Keff = (MODE == 2 && causal) ? min(K, m0 + 128) : K;
  int T = Keff >> 6;

  auto STAGE = [&](int slot, int k2, int c) {
    gl2lds16(pS[c] + k2, sm + slot * SLOT + dOf[c]);
  };

  int npre = T < 2 ? T : 2;
  for (int tt = 0; tt < npre; ++tt)
#pragma unroll
    for (int c = 0; c < 6; ++c) STAGE(tt, tt << 6, c);
  if (npre >= 2) vmwait<6>(); else vmwait<0>();
  __builtin_amdgcn_s_barrier();
  __builtin_amdgcn_sched_barrier(0);

  int sl = 0;
  for (int tq = 0; tq < T; ++tq) {
    u16* Sb = sm + sl * SLOT;
    int sl2 = sl + 2; if (sl2 >= 3) sl2 -= 3;
    const bool stg = (tq + 2 < T);
    const int k2 = (tq + 2) << 6;
    int cx = (l15 & 7);

    bf16x8 bfr[4][2], af[2][2];
#pragma unroll
    for (int j = 0; j < 4; ++j)
#pragma unroll
      for (int ks = 0; ks < 2; ++ks)
        bfr[j][ks] = *reinterpret_cast<const bf16x8*>(
            Sb + 8192 + (wc * 64 + j * 16 + l15) * 64 + ((((ks << 2) + quad) ^ cx) << 3));
#pragma unroll
    for (int i = 0; i < 2; ++i)
#pragma unroll
      for (int ks = 0; ks < 2; ++ks)
        af[i][ks] = *reinterpret_cast<const bf16x8*>(
            Sb + (wr * 64 + i * 16 + l15) * 64 + ((((ks << 2) + quad) ^ cx) << 3));
    if (stg) { STAGE(sl2, k2, 0); STAGE(sl2, k2, 1); STAGE(sl2, k2, 2); }
    __builtin_amdgcn_s_barrier();
    asm volatile("s_waitcnt lgkmcnt(0)" ::: "memory");
    __builtin_amdgcn_sched_barrier(0);
    __builtin_amdgcn_s_setprio(1);
#pragma unroll
    for (int i = 0; i < 2; ++i)
#pragma unroll
      for (int j = 0; j < 4; ++j) {
        acc[i][j] = __builtin_amdgcn_mfma_f32_16x16x32_bf16(af[i][0], bfr[j][0], acc[i][j], 0, 0, 0);
        acc[i][j] = __builtin_amdgcn_mfma_f32_16x16x32_bf16(af[i][1], bfr[j][1], acc[i][j], 0, 0, 0);
      }
    __builtin_amdgcn_s_setprio(0);
    __builtin_amdgcn_sched_barrier(0);
    __builtin_amdgcn_s_barrier();

    bf16x8 ag[2][2];
#pragma unroll
    for (int i = 0; i < 2; ++i)
#pragma unroll
      for (int ks = 0; ks < 2; ++ks)
        ag[i][ks] = *reinterpret_cast<const bf16x8*>(
            Sb + (wr * 64 + (i + 2) * 16 + l15) * 64 + ((((ks << 2) + quad) ^ cx) << 3));
    if (stg) { STAGE(sl2, k2, 3); STAGE(sl2, k2, 4); STAGE(sl2, k2, 5); }
    __builtin_amdgcn_s_barrier();
    asm volatile("s_waitcnt lgkmcnt(0)" ::: "memory");
    __builtin_amdgcn_sched_barrier(0);
    __builtin_amdgcn_s_setprio(1);
#pragma unroll
    for (int i = 0; i < 2; ++i)
#pragma unroll
      for (int j = 0; j < 4; ++j) {
        acc[i + 2][j] = __builtin_amdgcn_mfma_f32_16x16x32_bf16(ag[i][0], bfr[j][0], acc[i + 2][j], 0, 0, 0);
        acc[i + 2][j] = __builtin_amdgcn_mfma_f32_16x16x32_bf16(ag[i][1], bfr[j][1], acc[i + 2][j], 0, 0, 0);
      }
    __builtin_amdgcn_s_setprio(0);
    __builtin_amdgcn_sched_barrier(0);
    if (tq + 1 < T) {
      if (stg) vmwait<6>(); else vmwait<0>();
      __builtin_amdgcn_s_barrier();
      __builtin_amdgcn_sched_barrier(0);
    }
    sl = sl + 1; if (sl >= 3) sl = 0;
  }

  const float rs = 0.03857583749f;  // 1/sqrt(672)
#pragma unroll
  for (int i = 0; i < 4; i++) {
#pragma unroll
    for (int j = 0; j < 4; j++) {
      int col = n0 + wc * 64 + j * 16 + l15;
      if (col >= N) continue;
#pragma unroll
      for (int rr = 0; rr < 4; rr++) {
        int row = m0 + wr * 64 + i * 16 + quad * 4 + rr;
        if (row >= M) continue;
        float v = acc[i][j][rr];
        if (MODE == 1) v = (col <= row) ? v * rs * __expf(a1[col] - a2[row]) : 0.f;
        else if (MODE == 2) v = v * a1[row];
        if (OUTF32) C32[(long)row * ldc + col] = v;
        else        C16[(long)row * ldc + col] = f2b(v);
      }
    }
  }
}

// ---------------------------------------------------------------------------
// Phase-interleaved NT GEMM (bf16), BK=32 — kept for QK (K=672 % 64 != 0).
// ---------------------------------------------------------------------------
template <int BM, int MODE, int OUTF32>
__global__ __launch_bounds__(512, 1) void gemm_p(
    const u16* __restrict__ A, const u16* __restrict__ Bt, void* __restrict__ Cp,
    int M, int N, int K, int lda, int ldb, int ldc,
    long sAhi, long sAlo, long sBhi, long sBlo, long sChi, long sClo,
    const float* __restrict__ aux1, const float* __restrict__ aux2,
    int auxStride, int causal)
{
  constexpr int MFR   = BM / 32;
  constexpr int NPH   = MFR / 2;
  constexpr int SLOT  = (BM + 256) * 32;
  constexpr int ACH   = BM / 128;
  constexpr int LOADS = ACH + 2;
  __shared__ __align__(16) u16 sm[4 * SLOT];

  int gx = gridDim.x;
  int nwg = gx * gridDim.y;
  int flat = blockIdx.y * gx + blockIdx.x;
  int qq = nwg >> 3, r8 = nwg & 7;
  int xcd = flat & 7, seq = flat >> 3;
  int logical = (xcd < r8 ? xcd * (qq + 1) : r8 * (qq + 1) + (xcd - r8) * qq) + seq;
  int bx = logical % gx, by = logical / gx;
  int m0 = by * BM, n0 = bx * 256;
  if (MODE == 1 && n0 > m0 + BM - 1) return;

  int bz = blockIdx.z, bzh = bz >> 2, bzl = bz & 3;
  A  += bzh * sAhi + bzl * sAlo;
  Bt += bzh * sBhi + bzl * sBlo;
  const float* a1 = aux1 ? aux1 + (long)bz * auxStride : nullptr;
  const float* a2 = aux2 ? aux2 + (long)bz * auxStride : nullptr;
  u16*   C16 = (u16*)Cp + bzh * sChi + bzl * sClo;
  float* C32 = (float*)Cp + bzh * sChi + bzl * sClo;

  int t = threadIdx.x, lane = t & 63, w = t >> 6;
  int l15 = lane & 15, quad = lane >> 4;
  int wr = w >> 2, wc = w & 3;

  int srow = t >> 2;
  int swz = (((t & 3) ^ ((t >> 3) & 3)) * 8);
  const u16* pS[LOADS];
  int coff[LOADS];
#pragma unroll
  for (int c = 0; c < ACH; ++c) {
    pS[c] = A + (long)(m0 + c * 128 + srow) * lda + swz;
    coff[c] = c * 4096 + w * 512;
  }
#pragma unroll
  for (int c = 0; c < 2; ++c) {
    pS[ACH + c] = Bt + (long)(n0 + c * 128 + srow) * ldb + swz;
    coff[ACH + c] = BM * 32 + c * 4096 + w * 512;
  }

  int rswz = (quad ^ ((l15 >> 1) & 3)) * 8;
  int aoff = (wr * (BM / 2) + l15) * 32 + rswz;
  int boff = BM * 32 + (wc * 64 + l15) * 32 + rswz;

  f32x4 acc[MFR][4];
#pragma unroll
  for (int i = 0; i < MFR; i++)
#pragma unroll
    for (int j = 0; j < 4; j++) acc[i][j] = (f32x4){0.f, 0.f, 0.f, 0.f};

  int Keff = (MODE == 2 && causal) ? min(K, m0 + BM) : K;
  int T = Keff >> 5;

  auto STAGE1 = [&](int tt, int c) {
    gl2lds16(pS[c] + (tt << 5), sm + (tt & 3) * SLOT + coff[c]);
  };

  int npre = T < 3 ? T : 3;
  for (int tt = 0; tt < npre; ++tt)
#pragma unroll
    for (int c = 0; c < LOADS; ++c) STAGE1(tt, c);
  if (npre >= 3)      vmwait<2 * LOADS>();
  else if (npre == 2) vmwait<LOADS>();
  else                vmwait<0>();
  __builtin_amdgcn_s_barrier();
  __builtin_amdgcn_sched_barrier(0);

  for (int tq = 0; tq < T; ++tq) {
    u16* Sb = sm + (tq & 3) * SLOT;
    const bool stg = (tq + 3 < T);
    bf16x8 bf[4];
#pragma unroll
    for (int p = 0; p < NPH; ++p) {
      bf16x8 a0 = *reinterpret_cast<const bf16x8*>(Sb + aoff + (2 * p) * 512);
      bf16x8 a1v = *reinterpret_cast<const bf16x8*>(Sb + aoff + (2 * p + 1) * 512);
      if (p == 0) {
#pragma unroll
        for (int j = 0; j < 4; ++j)
          bf[j] = *reinterpret_cast<const bf16x8*>(Sb + boff + j * 512);
      }
      if (stg) {
#pragma unroll
        for (int c = p * LOADS / NPH; c < (p + 1) * LOADS / NPH; ++c)
          STAGE1(tq + 3, c);
      }
      __builtin_amdgcn_s_barrier();
      asm volatile("s_waitcnt lgkmcnt(0)" ::: "memory");
      __builtin_amdgcn_sched_barrier(0);
      __builtin_amdgcn_s_setprio(1);
#pragma unroll
      for (int j = 0; j < 4; ++j)
        acc[2 * p][j] = __builtin_amdgcn_mfma_f32_16x16x32_bf16(a0, bf[j], acc[2 * p][j], 0, 0, 0);
#pragma unroll
      for (int j = 0; j < 4; ++j)
        acc[2 * p + 1][j] = __builtin_amdgcn_mfma_f32_16x16x32_bf16(a1v, bf[j], acc[2 * p + 1][j], 0, 0, 0);
      __builtin_amdgcn_s_setprio(0);
      __builtin_amdgcn_sched_barrier(0);
    }
    if (tq + 1 < T) {
      if (tq + 3 < T)      vmwait<2 * LOADS>();
      else if (tq + 2 < T) vmwait<LOADS>();
      else                 vmwait<0>();
      __builtin_amdgcn_s_barrier();
      __builtin_amdgcn_sched_barrier(0);
    }
  }

  const float rs = 0.03857583749f;  // 1/sqrt(672)
#pragma unroll
  for (int i = 0; i < MFR; i++) {
#pragma unroll
    for (int j = 0; j < 4; j++) {
      int col = n0 + wc * 64 + j * 16 + l15;
      if (col >= N) continue;
#pragma unroll
      for (int rr = 0; rr < 4; rr++) {
        int row = m0 + wr * (BM / 2) + i * 16 + quad * 4 + rr;
        if (row >= M) continue;
        float v = acc[i][j][rr];
        if (MODE == 1) v = (col <= row) ? v * rs * __expf(a1[col] - a2[row]) : 0.f;
        else if (MODE == 2) v = v * a1[row];
        if (OUTF32) C32[(long)row * ldc + col] = v;
        else        C16[(long)row * ldc + col] = f2b(v);
      }
    }
  }
}

// ---------------------------------------------------------------------------
// transpose with row stride: out[c*R + r] = in[r*ldin + c]; F32IN: fp32 source
// ---------------------------------------------------------------------------
template <int F32IN>
__global__ __launch_bounds__(256) void transpose_any(
    const void* __restrict__ in, u16* __restrict__ out, int R, int C, int ldin,
    long inHi, long inLo, long outStride)
{
  __shared__ u16 tile[64][65];
  int bz = blockIdx.z, bzh = bz >> 2, bzl = bz & 3;
  const u16* in16 = (const u16*)in + bzh * inHi + bzl * inLo;
  const float* inf = (const float*)in + bzh * inHi + bzl * inLo;
  out += (long)bz * outStride;
  int r0 = blockIdx.y * 64, c0 = blockIdx.x * 64;
  int t = threadIdx.x;
  for (int idx = t; idx < 64 * 64; idx += 256) {
    int r = idx >> 6, c = idx & 63;
    int rr = r0 + r, cc = c0 + c;
    u16 v = 0;
    if (rr < R && cc < C) {
      long off = (long)rr * ldin + cc;
      v = F32IN ? f2b(inf[off]) : in16[off];
    }
    tile[r][c] = v;
  }
  __syncthreads();
  for (int idx = t; idx < 64 * 64; idx += 256) {
    int r = idx & 63, c = idx >> 6;
    int rr = r0 + r, cc = c0 + c;
    if (rr < R && cc < C) out[(long)cc * R + rr] = tile[r][c];
  }
}

// ---------------------------------------------------------------------------
// x fp32 -> bf16, 8/thread
__global__ __launch_bounds__(256) void convert_x(
    const float* __restrict__ x, u16* __restrict__ o)
{
  long i = ((long)blockIdx.x * 256 + threadIdx.x) * 8;
  if (i >= (long)4096 * EE) return;
  float4 a = *reinterpret_cast<const float4*>(x + i);
  float4 b = *reinterpret_cast<const float4*>(x + i + 4);
  u16 t8[8] = {f2b(a.x), f2b(a.y), f2b(a.z), f2b(a.w),
               f2b(b.x), f2b(b.y), f2b(b.z), f2b(b.w)};
  *reinterpret_cast<uint4*>(o + i) = *reinterpret_cast<uint4*>(t8);
}

// ---------------------------------------------------------------------------
// WT3 (128 x 2688 bf16): rows r<24: r=seg*8+j -> (j<4?W_ig:W_fg)[seg*H + c, j&3]
__global__ __launch_bounds__(256) void prep_wt3(
    const float* __restrict__ Wig, const float* __restrict__ Wfg,
    u16* __restrict__ WT3)
{
  int i = blockIdx.x * 256 + threadIdx.x;
  if (i >= 128 * HH) return;
  int r = i / HH, c = i % HH;
  float v = 0.f;
  if (r < 24) {
    int seg = r >> 3, j = r & 7;
    const float* W = (j < 4) ? Wig : Wfg;
    v = W[(long)(seg * HH + c) * 4 + (j & 3)];
  }
  WT3[i] = f2b(v);
}

// Wq|Wk|Wv fp32 -> bf16 packed (3 x 10752)
__global__ __launch_bounds__(256) void prep_wqkv(
    const float* __restrict__ Wq, const float* __restrict__ Wk,
    const float* __restrict__ Wv, u16* __restrict__ o)
{
  int i = blockIdx.x * 256 + threadIdx.x;
  if (i >= 3 * 10752) return;
  int m = i / 10752, j = i % 10752;
  const float* W = (m == 0) ? Wq : (m == 1) ? Wk : Wv;
  o[i] = f2b(W[j]);
}

// ---------------------------------------------------------------------------
// depthwise causal conv (KS=4) + bias + silu, 4 h/thread
__global__ __launch_bounds__(256) void conv_silu(
    const u16* __restrict__ xinner, const float* __restrict__ cw,
    const float* __restrict__ cb, u16* __restrict__ xca)
{
  long idx = (long)blockIdx.x * 256 + threadIdx.x;
  if (idx >= (long)BB * SS * HH / 4) return;
  int h4 = (int)(idx % (HH / 4)) * 4;
  long bs = idx / (HH / 4);
  int s = (int)(bs % SS);
  float4 acc = *reinterpret_cast<const float4*>(cb + h4);
#pragma unroll
  for (int w = 0; w < 4; w++) {
    int sp = s + w - 3;
    if (sp < 0) continue;
    uint2 xr = *reinterpret_cast<const uint2*>(xinner + (bs + w - 3) * H2 + h4);
    const u16* xh = (const u16*)&xr;
    float4 cwv = *reinterpret_cast<const float4*>(cw + w * HH + h4);
    acc.x += b2f(xh[0]) * cwv.x;
    acc.y += b2f(xh[1]) * cwv.y;
    acc.z += b2f(xh[2]) * cwv.z;
    acc.w += b2f(xh[3]) * cwv.w;
  }
  u16 o4[4] = {f2b(silu_f(acc.x)), f2b(silu_f(acc.y)),
               f2b(silu_f(acc.z)), f2b(silu_f(acc.w))};
  *reinterpret_cast<uint2*>(xca + bs * HH + h4) = *reinterpret_cast<uint2*>(o4);
}

// ---------------------------------------------------------------------------
// headwise 4x4 projections, outputs stay in (B,S,H) layout (no relayout)
__global__ __launch_bounds__(256) void headwise_qkv(
    const u16* __restrict__ xinner, const u16* __restrict__ xca,
    const u16* __restrict__ Wqkv,
    u16* __restrict__ q, u16* __restrict__ k, u16* __restrict__ v)
{
  int idx = blockIdx.x * 256 + threadIdx.x;
  if (idx >= BB * SS * NPHH) return;
  int nph = idx % NPHH;
  long bs = idx / NPHH;
  int cbase = nph * 4;
  uint2 xar = *reinterpret_cast<const uint2*>(xca + bs * HH + cbase);
  uint2 xmr = *reinterpret_cast<const uint2*>(xinner + bs * H2 + cbase);
  const u16* xa = (const u16*)&xar;
  const u16* xm = (const u16*)&xmr;
  float xaf[4], xmf[4];
#pragma unroll
  for (int d = 0; d < 4; d++) { xaf[d] = b2f(xa[d]); xmf[d] = b2f(xm[d]); }
  union { uint4 v4[2]; u16 h[16]; } wq, wk, wv;
  const uint4* wqp = reinterpret_cast<const uint4*>(Wqkv + nph * 16);
  const uint4* wkp = reinterpret_cast<const uint4*>(Wqkv + 10752 + nph * 16);
  const uint4* wvp = reinterpret_cast<const uint4*>(Wqkv + 21504 + nph * 16);
  wq.v4[0] = wqp[0]; wq.v4[1] = wqp[1];
  wk.v4[0] = wkp[0]; wk.v4[1] = wkp[1];
  wv.v4[0] = wvp[0]; wv.v4[1] = wvp[1];
  u16 qo[4], ko[4], vo[4];
#pragma unroll
  for (int o = 0; o < 4; o++) {
    float aq = 0.f, ak = 0.f, av = 0.f;
#pragma unroll
    for (int d = 0; d < 4; d++) {
      aq += xaf[d] * b2f(wq.h[d * 4 + o]);
      ak += xaf[d] * b2f(wk.h[d * 4 + o]);
      av += xmf[d] * b2f(wv.h[d * 4 + o]);
    }
    qo[o] = f2b(aq); ko[o] = f2b(ak); vo[o] = f2b(av);
  }
  long ob = bs * HH + cbase;
  *reinterpret_cast<uint2*>(q + ob) = *reinterpret_cast<uint2*>(qo);
  *reinterpret_cast<uint2*>(k + ob) = *reinterpret_cast<uint2*>(ko);
  *reinterpret_cast<uint2*>(v + ob) = *reinterpret_cast<uint2*>(vo);
}

// ---------------------------------------------------------------------------
// per (b,n): ipre/fpre from G (12288x24) + bias; cs=cumsum(logsig(f));
// a=i-cs; rmax=prefmax(a); m=cs+rmax
__global__ __launch_bounds__(1024) void scan_kernel(
    const float* __restrict__ G, const float* __restrict__ big,
    const float* __restrict__ bfg,
    float* __restrict__ avec, float* __restrict__ rmaxvec, float* __restrict__ mvec)
{
  __shared__ float buf[2][SS];
  __shared__ float isave[SS];
  __shared__ float cssave[SS];
  int bn = blockIdx.x;
  int b = bn >> 2, n = bn & 3;
  int t = threadIdx.x;
  float bi = big[n], bf = bfg[n];
  for (int i = t; i < SS; i += 1024) {
    long tk = (long)b * SS + i;
    float ip = G[tk * 24 + n] + G[(4096 + tk) * 24 + 8 + n] +
               G[(8192 + tk) * 24 + 16 + n] + bi;
    float fp = G[tk * 24 + 4 + n] + G[(4096 + tk) * 24 + 12 + n] +
               G[(8192 + tk) * 24 + 20 + n] + bf;
    isave[i] = ip;
    buf[0][i] = logsig_f(fp);
  }
  __syncthreads();
  int src = 0;
  for (int off = 1; off < SS; off <<= 1) {
    int dst = 1 - src;
    for (int i = t; i < SS; i += 1024) {
      float x = buf[src][i];
      if (i >= off) x += buf[src][i - off];
      buf[dst][i] = x;
    }
    __syncthreads();
    src = dst;
  }
  for (int i = t; i < SS; i += 1024) {
    float cs = buf[src][i];
    cssave[i] = cs;
    float a = isave[i] - cs;
    avec[(long)bn * SS + i] = a;
    buf[src][i] = a;
  }
  __syncthreads();
  for (int off = 1; off < SS; off <<= 1) {
    int dst = 1 - src;
    for (int i = t; i < SS; i += 1024) {
      float x = buf[src][i];
      if (i >= off) x = fmaxf(x, buf[src][i - off]);
      buf[dst][i] = x;
    }
    __syncthreads();
    src = dst;
  }
  for (int i = t; i < SS; i += 1024) {
    rmaxvec[(long)bn * SS + i] = buf[src][i];
    mvec[(long)bn * SS + i] = cssave[i] + buf[src][i];
  }
}

// ---------------------------------------------------------------------------
// causal row sums of P -> inv_n (vectorized uint4 + in-bounds scalar tail)
__global__ __launch_bounds__(256) void rowsum_kernel(
    const u16* __restrict__ P, const float* __restrict__ mvec, float* __restrict__ invn,
    long Pstride)
{
  int bz = blockIdx.z;
  P += (long)bz * Pstride;
  mvec += (long)bz * SS;
  invn += (long)bz * SS;
  int row = (blockIdx.x * 256 + threadIdx.x) >> 6;
  int lane = threadIdx.x & 63;
  if (row >= SS) return;
  const u16* pr = P + (long)row * SS;
  float s = 0.f;
  int j0 = lane * 8;
  for (; j0 + 7 <= row; j0 += 512) {
    uint4 u = *reinterpret_cast<const uint4*>(pr + j0);
    const u16* e = (const u16*)&u;
#pragma unroll
    for (int q = 0; q < 8; ++q) s += b2f(e[q]);
  }
  if (j0 <= row) {
    for (int q = 0; j0 + q <= row; ++q) s += b2f(pr[j0 + q]);
  }
#pragma unroll
  for (int off = 32; off > 0; off >>= 1) s += __shfl_down(s, off);
  if (lane == 0) {
    float n = fmaxf(fabsf(s), __expf(-mvec[row]));
    invn[row] = 1.f / (n + 1e-6f);
  }
}

// ---------------------------------------------------------------------------
// multi-head layernorm + skip + gate (paired u32 bf16 loads)
__global__ __launch_bounds__(256) void ln_skip_gate(
    const u16* __restrict__ h, const u16* __restrict__ xca,
    const u16* __restrict__ xinner, const float* __restrict__ normw,
    const float* __restrict__ skipw, u16* __restrict__ hs)
{
  int row = (blockIdx.x * 256 + threadIdx.x) >> 6;  // (b*NH+n)*S + s
  int lane = threadIdx.x & 63;
  if (row >= BB * NHH * SS) return;
  int s = row % SS;
  int n = (row / SS) % NHH;
  int b = row / (SS * NHH);
  const u16* hr = h + (long)row * DHH;
  float sum = 0.f, ss = 0.f;
  float vx[6], vy[6];
#pragma unroll
  for (int i = 0; i < 6; ++i) {
    int d2 = lane + i * 64;
    float x = 0.f, y = 0.f;
    if (d2 < DHH / 2) {
      u32 u = *reinterpret_cast<const u32*>(hr + d2 * 2);
      x = b2f((u16)u); y = b2f((u16)(u >> 16));
    }
    vx[i] = x; vy[i] = y;
    sum += x + y; ss += x * x + y * y;
  }
#pragma unroll
  for (int off = 32; off > 0; off >>= 1) { sum += __shfl_down(sum, off); ss += __shfl_down(ss, off); }
  sum = __shfl(sum, 0); ss = __shfl(ss, 0);
  float mu = sum / (float)DHH;
  float var = ss / (float)DHH - mu * mu;
  float rstd = rsqrtf(var + 1e-5f);
  long bs = (long)b * SS + s;
#pragma unroll
  for (int i = 0; i < 6; ++i) {
    int d2 = lane + i * 64;
    if (d2 >= DHH / 2) continue;
    int c = n * DHH + d2 * 2;
    float2 nw = *reinterpret_cast<const float2*>(normw + c);
    float2 sw = *reinterpret_cast<const float2*>(skipw + c);
    u32 xcu = *reinterpret_cast<const u32*>(xca + bs * HH + c);
    u32 zu  = *reinterpret_cast<const u32*>(xinner + bs * H2 + HH + c);
    float h0 = (vx[i] - mu) * rstd * nw.x + sw.x * b2f((u16)xcu);
    float h1 = (vy[i] - mu) * rstd * nw.y + sw.y * b2f((u16)(xcu >> 16));
    float o0 = h0 * silu_f(b2f((u16)zu));
    float o1 = h1 * silu_f(b2f((u16)(zu >> 16)));
    u32 ou = (u32)f2b(o0) | ((u32)f2b(o1) << 16);
    *reinterpret_cast<u32*>(hs + bs * HH + c) = ou;
  }
}

// ---------------------------------------------------------------------------
__global__ __launch_bounds__(256) void fill_sentinel(float* out, float v, long n) {
  long i = (long)blockIdx.x * 256 + threadIdx.x;
  if (i < n) out[i] = v;
}

// ---------------------------------------------------------------------------
extern "C" void kernel_launch(void* const* d_in, const int* in_sizes, int n_in,
                              void* d_out, int out_size, void* d_ws, size_t ws_size,
                              hipStream_t stream)
{
  const float* x      = (const float*)d_in[0];
  const float* W_in   = (const float*)d_in[1];
  const float* conv_w = (const float*)d_in[2];
  const float* conv_b = (const float*)d_in[3];
  const float* Wq     = (const float*)d_in[4];
  const float* Wk     = (const float*)d_in[5];
  const float* Wv     = (const float*)d_in[6];
  const float* W_ig   = (const float*)d_in[7];
  const float* b_ig   = (const float*)d_in[8];
  const float* W_fg   = (const float*)d_in[9];
  const float* b_fg   = (const float*)d_in[10];
  const float* norm_w = (const float*)d_in[11];
  const float* skipw  = (const float*)d_in[12];
  const float* W_out  = (const float*)d_in[13];
  float* out = (float*)d_out;
  const long SD = (long)SS * DHH;     // head slice elems
  const long SP = (long)SS * SS;
  const long BH = (long)SS * HH;      // per-batch elems of (S,H)

  u16* ws = (u16*)d_ws;
  size_t off = 0;
  auto alloc = [&](size_t n) { u16* p = ws + off; off += n; return p; };
  u16* x_inner = alloc((size_t)4096 * H2);
  u16* xca     = alloc((size_t)4096 * HH);
  u16* qb      = alloc((size_t)4096 * HH);   // W_inT -> q -> hs
  u16* kb      = alloc((size_t)4096 * HH);   // xbf -> k -> h
  u16* vb      = alloc((size_t)4096 * HH);   // v -> W_outT
  float* fvec  = (float*)(ws + off);
  off += 4 * 16384 * 2;
  float* avec    = fvec;
  float* rmaxvec = avec + 16384;
  float* mvec    = rmaxvec + 16384;
  float* invn    = mvec + 16384;
  u16* vt8 = alloc((size_t)8 * SD);
  u16* Pb8 = alloc((size_t)8 * SP);
  size_t need = off * 2;
  long outn = (long)4096 * EE;

  if (ws_size < need) {
    fill_sentinel<<<dim3((outn + 255) / 256), 256, 0, stream>>>(
        out, 200.f + 0.01f * (float)(ws_size >> 20), outn);
    return;
  }

  // overlays
  u16* W_inT  = qb;                       // consumed before headwise writes q
  u16* xbf    = kb;                       // consumed before headwise writes k
  u16* W_outT = vb;                       // written after v's last use
  u16* hbuf   = kb;                       // h (bn,S,DH) after k's last use
  u16* hsbuf  = qb;                       // hs after q's last use
  u16* WT3    = Pb8;                      // 128x2688, consumed before QK
  float* G    = (float*)(Pb8 + 344064);   // 12288x24 fp32, consumed before QK
  u16* Wqkv   = Pb8 + 933888;             // 3x10752, consumed before QK

  prep_wt3<<<dim3(1344, 1, 1), 256, 0, stream>>>(W_ig, W_fg, WT3);
  prep_wqkv<<<dim3(126, 1, 1), 256, 0, stream>>>(Wq, Wk, Wv, Wqkv);
  transpose_any<1><<<dim3(84, 32, 1), 256, 0, stream>>>(
      W_in, W_inT, EE, H2, H2, 0, 0, 0);
  convert_x<<<dim3(4096, 1, 1), 256, 0, stream>>>(x, xbf);
  // x_inner = x @ W_in : M=4096 N=5376 K=2048 (256x256 8-phase, 336 blocks)
  gemm256<0, 0><<<dim3(21, 16, 1), 512, 0, stream>>>(
      xbf, W_inT, x_inner, 4096, H2, EE, EE, EE, H2,
      0, 0, 0, 0, 0, 0, nullptr, nullptr, 0, 0);
  conv_silu<<<dim3(10752, 1, 1), 256, 0, stream>>>(x_inner, conv_w, conv_b, xca);
  headwise_qkv<<<dim3(10752, 1, 1), 256, 0, stream>>>(
      x_inner, xca, Wqkv, qb, kb, vb);
  // gates: [q;k;v] (12288 x 2688) @ WT3^T -> G (12288 x 24), K=2688=42*64
  gemm8<0, 1><<<dim3(1, 96, 1), 512, 0, stream>>>(
      qb, WT3, G, 12288, 24, HH, HH, HH, 24,
      0, 0, 0, 0, 0, 0, nullptr, nullptr, 0, 0);
  scan_kernel<<<dim3(8, 1, 1), 1024, 0, stream>>>(G, b_ig, b_fg, avec, rmaxvec, mvec);
  // v^T per (b,n): (DH, S)
  transpose_any<0><<<dim3(11, 32, 8), 256, 0, stream>>>(
      vb, vt8, SS, DHH, HH, BH, DHH, SD);
  // P = (q k^T / sqrt(DH)) * exp(a[col]-rmax[row]), causal; K=672 -> BK32 path
  gemm_p<256, 1, 0><<<dim3(8, 8, 8), 512, 0, stream>>>(
      qb, kb, Pb8, SS, SS, DHH, HH, HH, SS,
      BH, DHH, BH, DHH, 4 * SP, SP, avec, rmaxvec, SS, 0);
  rowsum_kernel<<<dim3(512, 1, 8), 256, 0, stream>>>(Pb8, mvec, invn, SP);
  // h = (P @ v) * inv_n, into (bn, S, DH); Keff = m0+128 (mult of 64 ok);
  // B over-reads vt8 rows 672..767 (in-bounds garbage, masked by col<N)
  gemm8<2, 0><<<dim3(3, 16, 8), 512, 0, stream>>>(
      Pb8, vt8, hbuf, SS, DHH, SS, SS, SS, DHH,
      4 * SP, SP, 4 * SD, SD, 4 * SD, SD, invn, nullptr, SS, 1);
  transpose_any<1><<<dim3(32, 42, 1), 256, 0, stream>>>(
      W_out, W_outT, HH, EE, EE, 0, 0, 0);
  ln_skip_gate<<<dim3(4096, 1, 1), 256, 0, stream>>>(
      hbuf, xca, x_inner, norm_w, skipw, hsbuf);
  gemm8<0, 1><<<dim3(8, 32, 1), 512, 0, stream>>>(
      hsbuf, W_outT, out, 4096, EE, HH, HH, HH, EE,
      0, 0, 0, 0, 0, 0, nullptr, nullptr, 0, 0);
}

// Round 5
// 651.490 us; speedup vs baseline: 1.0635x; 1.0635x over previous
//
#include <hip/hip_runtime.h>

typedef unsigned short u16;
typedef unsigned int u32;
typedef __bf16 bf16x8 __attribute__((ext_vector_type(8)));
typedef float f32x4 __attribute__((ext_vector_type(4)));

#define BB   2
#define SS   2048
#define EE   2048
#define HH   2688
#define NHH  4
#define DHH  672
#define NPHH 672
#define H2   5376
#define H3   8064

__device__ __forceinline__ float b2f(u16 u) {
  union { unsigned int i; float f; } c; c.i = ((unsigned int)u) << 16; return c.f;
}
__device__ __forceinline__ u16 f2b(float f) {
  union { float f; unsigned int i; } c; c.f = f;
  unsigned int i = c.i;
  return (u16)((i + 0x7FFFu + ((i >> 16) & 1u)) >> 16);
}
__device__ __forceinline__ float silu_f(float x) { return x / (1.f + __expf(-x)); }
__device__ __forceinline__ float logsig_f(float f) {
  return (f >= 0.f) ? -log1pf(__expf(-f)) : (f - log1pf(__expf(f)));
}

// async global->LDS, 16B per lane; dst wave-uniform base, HW adds lane*16B
__device__ __forceinline__ void gl2lds16(const u16* g, u16* s) {
  __builtin_amdgcn_global_load_lds(
      (const __attribute__((address_space(1))) u32*)g,
      (__attribute__((address_space(3))) u32*)s, 16, 0, 0);
}

template <int N> __device__ __forceinline__ void vmwait() {
  asm volatile("s_waitcnt vmcnt(%0)" :: "n"(N) : "memory");
}

// ---------------------------------------------------------------------------
// gemm8: 2-phase NT GEMM (bf16), BK=64, 128x256 tile, 8 waves, ring-3 LDS,
// prefetch lead 2, vmcnt(6) per tile (never 0 mid-loop). Measured best
// per-makespan structure (r3: x@W_in 127us). XOR chunk swizzle both sides.
// MODE 0 plain; MODE 2 PV epilogue (row scale, causal K-cap). OUTF32: fp32.
// Requires: M % 128 == 0, K % 64 == 0. N masked on store; B staging may
// over-read up to 255 rows past N (callers guarantee in-bounds memory).
// ---------------------------------------------------------------------------
template <int MODE, int OUTF32>
__global__ __launch_bounds__(512, 1) void gemm8(
    const u16* __restrict__ A, const u16* __restrict__ Bt, void* __restrict__ Cp,
    int M, int N, int K, int lda, int ldb, int ldc,
    long sAhi, long sAlo, long sBhi, long sBlo, long sChi, long sClo,
    const float* __restrict__ aux1, const float* __restrict__ aux2,
    int auxStride, int causal)
{
  constexpr int SLOT = (128 + 256) * 64;   // u16 per ring slot (48 KiB)
  __shared__ __align__(16) u16 sm[3 * SLOT];  // 144 KiB

  int gx = gridDim.x;
  int nwg = gx * gridDim.y;
  int flat = blockIdx.y * gx + blockIdx.x;
  int qq = nwg >> 3, r8 = nwg & 7;
  int xcd = flat & 7, seq = flat >> 3;
  int logical = (xcd < r8 ? xcd * (qq + 1) : r8 * (qq + 1) + (xcd - r8) * qq) + seq;
  int bx = logical % gx, by = logical / gx;
  int m0 = by * 128, n0 = bx * 256;
  if (MODE == 1 && n0 > m0 + 127) return;

  int bz = blockIdx.z, bzh = bz >> 2, bzl = bz & 3;
  A  += bzh * sAhi + bzl * sAlo;
  Bt += bzh * sBhi + bzl * sBlo;
  const float* a1 = aux1 ? aux1 + (long)bz * auxStride : nullptr;
  const float* a2 = aux2 ? aux2 + (long)bz * auxStride : nullptr;
  u16*   C16 = (u16*)Cp + bzh * sChi + bzl * sClo;
  float* C32 = (float*)Cp + bzh * sChi + bzl * sClo;

  int t = threadIdx.x, lane = t & 63, w = t >> 6;
  int l15 = lane & 15, quad = lane >> 4;
  int wr = w >> 2, wc = w & 3;

  int srow = t >> 3;
  int sw8 = ((t & 7) ^ (srow & 7)) * 8;
  const u16* pS[6];
  int dOf[6];
#pragma unroll
  for (int c = 0; c < 2; ++c) {
    pS[c] = A + (long)(m0 + c * 64 + srow) * lda + sw8;
    dOf[c] = c * 4096 + w * 512;
  }
#pragma unroll
  for (int c = 0; c < 4; ++c) {
    pS[2 + c] = Bt + (long)(n0 + c * 64 + srow) * ldb + sw8;
    dOf[2 + c] = 8192 + c * 4096 + w * 512;
  }

  f32x4 acc[4][4];
#pragma unroll
  for (int i = 0; i < 4; i++)
#pragma unroll
    for (int j = 0; j < 4; j++) acc[i][j] = (f32x4){0.f, 0.f, 0.f, 0.f};

  int Keff = (MODE == 2 && causal) ? min(K, m0 + 128) : K;
  int T = Keff >> 6;

  auto STAGE = [&](int slot, int k2, int c) {
    gl2lds16(pS[c] + k2, sm + slot * SLOT + dOf[c]);
  };

  int npre = T < 2 ? T : 2;
  for (int tt = 0; tt < npre; ++tt)
#pragma unroll
    for (int c = 0; c < 6; ++c) STAGE(tt, tt << 6, c);
  if (npre >= 2) vmwait<6>(); else vmwait<0>();
  __builtin_amdgcn_s_barrier();
  __builtin_amdgcn_sched_barrier(0);

  int sl = 0;
  for (int tq = 0; tq < T; ++tq) {
    u16* Sb = sm + sl * SLOT;
    int sl2 = sl + 2; if (sl2 >= 3) sl2 -= 3;
    const bool stg = (tq + 2 < T);
    const int k2 = (tq + 2) << 6;
    int cx = (l15 & 7);

    bf16x8 bfr[4][2], af[2][2];
#pragma unroll
    for (int j = 0; j < 4; ++j)
#pragma unroll
      for (int ks = 0; ks < 2; ++ks)
        bfr[j][ks] = *reinterpret_cast<const bf16x8*>(
            Sb + 8192 + (wc * 64 + j * 16 + l15) * 64 + ((((ks << 2) + quad) ^ cx) << 3));
#pragma unroll
    for (int i = 0; i < 2; ++i)
#pragma unroll
      for (int ks = 0; ks < 2; ++ks)
        af[i][ks] = *reinterpret_cast<const bf16x8*>(
            Sb + (wr * 64 + i * 16 + l15) * 64 + ((((ks << 2) + quad) ^ cx) << 3));
    if (stg) { STAGE(sl2, k2, 0); STAGE(sl2, k2, 1); STAGE(sl2, k2, 2); }
    __builtin_amdgcn_s_barrier();
    asm volatile("s_waitcnt lgkmcnt(0)" ::: "memory");
    __builtin_amdgcn_sched_barrier(0);
    __builtin_amdgcn_s_setprio(1);
#pragma unroll
    for (int i = 0; i < 2; ++i)
#pragma unroll
      for (int j = 0; j < 4; ++j) {
        acc[i][j] = __builtin_amdgcn_mfma_f32_16x16x32_bf16(af[i][0], bfr[j][0], acc[i][j], 0, 0, 0);
        acc[i][j] = __builtin_amdgcn_mfma_f32_16x16x32_bf16(af[i][1], bfr[j][1], acc[i][j], 0, 0, 0);
      }
    __builtin_amdgcn_s_setprio(0);
    __builtin_amdgcn_sched_barrier(0);
    __builtin_amdgcn_s_barrier();

    bf16x8 ag[2][2];
#pragma unroll
    for (int i = 0; i < 2; ++i)
#pragma unroll
      for (int ks = 0; ks < 2; ++ks)
        ag[i][ks] = *reinterpret_cast<const bf16x8*>(
            Sb + (wr * 64 + (i + 2) * 16 + l15) * 64 + ((((ks << 2) + quad) ^ cx) << 3));
    if (stg) { STAGE(sl2, k2, 3); STAGE(sl2, k2, 4); STAGE(sl2, k2, 5); }
    __builtin_amdgcn_s_barrier();
    asm volatile("s_waitcnt lgkmcnt(0)" ::: "memory");
    __builtin_amdgcn_sched_barrier(0);
    __builtin_amdgcn_s_setprio(1);
#pragma unroll
    for (int i = 0; i < 2; ++i)
#pragma unroll
      for (int j = 0; j < 4; ++j) {
        acc[i + 2][j] = __builtin_amdgcn_mfma_f32_16x16x32_bf16(ag[i][0], bfr[j][0], acc[i + 2][j], 0, 0, 0);
        acc[i + 2][j] = __builtin_amdgcn_mfma_f32_16x16x32_bf16(ag[i][1], bfr[j][1], acc[i + 2][j], 0, 0, 0);
      }
    __builtin_amdgcn_s_setprio(0);
    __builtin_amdgcn_sched_barrier(0);
    if (tq + 1 < T) {
      if (stg) vmwait<6>(); else vmwait<0>();
      __builtin_amdgcn_s_barrier();
      __builtin_amdgcn_sched_barrier(0);
    }
    sl = sl + 1; if (sl >= 3) sl = 0;
  }

  const float rs = 0.03857583749f;  // 1/sqrt(672)
#pragma unroll
  for (int i = 0; i < 4; i++) {
#pragma unroll
    for (int j = 0; j < 4; j++) {
      int col = n0 + wc * 64 + j * 16 + l15;
      if (col >= N) continue;
#pragma unroll
      for (int rr = 0; rr < 4; rr++) {
        int row = m0 + wr * 64 + i * 16 + quad * 4 + rr;
        if (row >= M) continue;
        float v = acc[i][j][rr];
        if (MODE == 1) v = (col <= row) ? v * rs * __expf(a1[col] - a2[row]) : 0.f;
        else if (MODE == 2) v = v * a1[row];
        if (OUTF32) C32[(long)row * ldc + col] = v;
        else        C16[(long)row * ldc + col] = f2b(v);
      }
    }
  }
}

// ---------------------------------------------------------------------------
// Phase-interleaved NT GEMM (bf16), BK=32 — kept for QK (K=672 % 64 != 0).
// Best measured per-CU rate (r2: 4.0 TF/CU busy).
// ---------------------------------------------------------------------------
template <int BM, int MODE, int OUTF32>
__global__ __launch_bounds__(512, 1) void gemm_p(
    const u16* __restrict__ A, const u16* __restrict__ Bt, void* __restrict__ Cp,
    int M, int N, int K, int lda, int ldb, int ldc,
    long sAhi, long sAlo, long sBhi, long sBlo, long sChi, long sClo,
    const float* __restrict__ aux1, const float* __restrict__ aux2,
    int auxStride, int causal)
{
  constexpr int MFR   = BM / 32;
  constexpr int NPH   = MFR / 2;
  constexpr int SLOT  = (BM + 256) * 32;
  constexpr int ACH   = BM / 128;
  constexpr int LOADS = ACH + 2;
  __shared__ __align__(16) u16 sm[4 * SLOT];

  int gx = gridDim.x;
  int nwg = gx * gridDim.y;
  int flat = blockIdx.y * gx + blockIdx.x;
  int qq = nwg >> 3, r8 = nwg & 7;
  int xcd = flat & 7, seq = flat >> 3;
  int logical = (xcd < r8 ? xcd * (qq + 1) : r8 * (qq + 1) + (xcd - r8) * qq) + seq;
  int bx = logical % gx, by = logical / gx;
  int m0 = by * BM, n0 = bx * 256;
  if (MODE == 1 && n0 > m0 + BM - 1) return;

  int bz = blockIdx.z, bzh = bz >> 2, bzl = bz & 3;
  A  += bzh * sAhi + bzl * sAlo;
  Bt += bzh * sBhi + bzl * sBlo;
  const float* a1 = aux1 ? aux1 + (long)bz * auxStride : nullptr;
  const float* a2 = aux2 ? aux2 + (long)bz * auxStride : nullptr;
  u16*   C16 = (u16*)Cp + bzh * sChi + bzl * sClo;
  float* C32 = (float*)Cp + bzh * sChi + bzl * sClo;

  int t = threadIdx.x, lane = t & 63, w = t >> 6;
  int l15 = lane & 15, quad = lane >> 4;
  int wr = w >> 2, wc = w & 3;

  int srow = t >> 2;
  int swz = (((t & 3) ^ ((t >> 3) & 3)) * 8);
  const u16* pS[LOADS];
  int coff[LOADS];
#pragma unroll
  for (int c = 0; c < ACH; ++c) {
    pS[c] = A + (long)(m0 + c * 128 + srow) * lda + swz;
    coff[c] = c * 4096 + w * 512;
  }
#pragma unroll
  for (int c = 0; c < 2; ++c) {
    pS[ACH + c] = Bt + (long)(n0 + c * 128 + srow) * ldb + swz;
    coff[ACH + c] = BM * 32 + c * 4096 + w * 512;
  }

  int rswz = (quad ^ ((l15 >> 1) & 3)) * 8;
  int aoff = (wr * (BM / 2) + l15) * 32 + rswz;
  int boff = BM * 32 + (wc * 64 + l15) * 32 + rswz;

  f32x4 acc[MFR][4];
#pragma unroll
  for (int i = 0; i < MFR; i++)
#pragma unroll
    for (int j = 0; j < 4; j++) acc[i][j] = (f32x4){0.f, 0.f, 0.f, 0.f};

  int Keff = (MODE == 2 && causal) ? min(K, m0 + BM) : K;
  int T = Keff >> 5;

  auto STAGE1 = [&](int tt, int c) {
    gl2lds16(pS[c] + (tt << 5), sm + (tt & 3) * SLOT + coff[c]);
  };

  int npre = T < 3 ? T : 3;
  for (int tt = 0; tt < npre; ++tt)
#pragma unroll
    for (int c = 0; c < LOADS; ++c) STAGE1(tt, c);
  if (npre >= 3)      vmwait<2 * LOADS>();
  else if (npre == 2) vmwait<LOADS>();
  else                vmwait<0>();
  __builtin_amdgcn_s_barrier();
  __builtin_amdgcn_sched_barrier(0);

  for (int tq = 0; tq < T; ++tq) {
    u16* Sb = sm + (tq & 3) * SLOT;
    const bool stg = (tq + 3 < T);
    bf16x8 bf[4];
#pragma unroll
    for (int p = 0; p < NPH; ++p) {
      bf16x8 a0 = *reinterpret_cast<const bf16x8*>(Sb + aoff + (2 * p) * 512);
      bf16x8 a1v = *reinterpret_cast<const bf16x8*>(Sb + aoff + (2 * p + 1) * 512);
      if (p == 0) {
#pragma unroll
        for (int j = 0; j < 4; ++j)
          bf[j] = *reinterpret_cast<const bf16x8*>(Sb + boff + j * 512);
      }
      if (stg) {
#pragma unroll
        for (int c = p * LOADS / NPH; c < (p + 1) * LOADS / NPH; ++c)
          STAGE1(tq + 3, c);
      }
      __builtin_amdgcn_s_barrier();
      asm volatile("s_waitcnt lgkmcnt(0)" ::: "memory");
      __builtin_amdgcn_sched_barrier(0);
      __builtin_amdgcn_s_setprio(1);
#pragma unroll
      for (int j = 0; j < 4; ++j)
        acc[2 * p][j] = __builtin_amdgcn_mfma_f32_16x16x32_bf16(a0, bf[j], acc[2 * p][j], 0, 0, 0);
#pragma unroll
      for (int j = 0; j < 4; ++j)
        acc[2 * p + 1][j] = __builtin_amdgcn_mfma_f32_16x16x32_bf16(a1v, bf[j], acc[2 * p + 1][j], 0, 0, 0);
      __builtin_amdgcn_s_setprio(0);
      __builtin_amdgcn_sched_barrier(0);
    }
    if (tq + 1 < T) {
      if (tq + 3 < T)      vmwait<2 * LOADS>();
      else if (tq + 2 < T) vmwait<LOADS>();
      else                 vmwait<0>();
      __builtin_amdgcn_s_barrier();
      __builtin_amdgcn_sched_barrier(0);
    }
  }

  const float rs = 0.03857583749f;  // 1/sqrt(672)
#pragma unroll
  for (int i = 0; i < MFR; i++) {
#pragma unroll
    for (int j = 0; j < 4; j++) {
      int col = n0 + wc * 64 + j * 16 + l15;
      if (col >= N) continue;
#pragma unroll
      for (int rr = 0; rr < 4; rr++) {
        int row = m0 + wr * (BM / 2) + i * 16 + quad * 4 + rr;
        if (row >= M) continue;
        float v = acc[i][j][rr];
        if (MODE == 1) v = (col <= row) ? v * rs * __expf(a1[col] - a2[row]) : 0.f;
        else if (MODE == 2) v = v * a1[row];
        if (OUTF32) C32[(long)row * ldc + col] = v;
        else        C16[(long)row * ldc + col] = f2b(v);
      }
    }
  }
}

// ---------------------------------------------------------------------------
// transpose with row stride: out[c*R + r] = in[r*ldin + c]; F32IN: fp32 source
// ---------------------------------------------------------------------------
template <int F32IN>
__global__ __launch_bounds__(256) void transpose_any(
    const void* __restrict__ in, u16* __restrict__ out, int R, int C, int ldin,
    long inHi, long inLo, long outStride)
{
  __shared__ u16 tile[64][65];
  int bz = blockIdx.z, bzh = bz >> 2, bzl = bz & 3;
  const u16* in16 = (const u16*)in + bzh * inHi + bzl * inLo;
  const float* inf = (const float*)in + bzh * inHi + bzl * inLo;
  out += (long)bz * outStride;
  int r0 = blockIdx.y * 64, c0 = blockIdx.x * 64;
  int t = threadIdx.x;
  for (int idx = t; idx < 64 * 64; idx += 256) {
    int r = idx >> 6, c = idx & 63;
    int rr = r0 + r, cc = c0 + c;
    u16 v = 0;
    if (rr < R && cc < C) {
      long off = (long)rr * ldin + cc;
      v = F32IN ? f2b(inf[off]) : in16[off];
    }
    tile[r][c] = v;
  }
  __syncthreads();
  for (int idx = t; idx < 64 * 64; idx += 256) {
    int r = idx & 63, c = idx >> 6;
    int rr = r0 + r, cc = c0 + c;
    if (rr < R && cc < C) out[(long)cc * R + rr] = tile[r][c];
  }
}

// ---------------------------------------------------------------------------
// x fp32 -> bf16, 8/thread
__global__ __launch_bounds__(256) void convert_x(
    const float* __restrict__ x, u16* __restrict__ o)
{
  long i = ((long)blockIdx.x * 256 + threadIdx.x) * 8;
  if (i >= (long)4096 * EE) return;
  float4 a = *reinterpret_cast<const float4*>(x + i);
  float4 b = *reinterpret_cast<const float4*>(x + i + 4);
  u16 t8[8] = {f2b(a.x), f2b(a.y), f2b(a.z), f2b(a.w),
               f2b(b.x), f2b(b.y), f2b(b.z), f2b(b.w)};
  *reinterpret_cast<uint4*>(o + i) = *reinterpret_cast<uint4*>(t8);
}

// ---------------------------------------------------------------------------
// Wq|Wk|Wv fp32 -> bf16 packed (3 x 10752)
__global__ __launch_bounds__(256) void prep_wqkv(
    const float* __restrict__ Wq, const float* __restrict__ Wk,
    const float* __restrict__ Wv, u16* __restrict__ o)
{
  int i = blockIdx.x * 256 + threadIdx.x;
  if (i >= 3 * 10752) return;
  int m = i / 10752, j = i % 10752;
  const float* W = (m == 0) ? Wq : (m == 1) ? Wk : Wv;
  o[i] = f2b(W[j]);
}

// ---------------------------------------------------------------------------
// FUSED: depthwise causal conv (KS=4) + bias + silu + headwise 4x4 q/k/v.
// One thread per (bs, nph). Tap w=3 IS x_m -> reused for the v-projection.
// Writes xca (needed later by ln_skip_gate) and q,k,v in (B,S,H) layout.
// ---------------------------------------------------------------------------
__global__ __launch_bounds__(256) void conv_head(
    const u16* __restrict__ xinner, const float* __restrict__ cw,
    const float* __restrict__ cb, const u16* __restrict__ Wqkv,
    u16* __restrict__ xca, u16* __restrict__ q, u16* __restrict__ k,
    u16* __restrict__ v)
{
  long idx = (long)blockIdx.x * 256 + threadIdx.x;
  if (idx >= (long)BB * SS * NPHH) return;
  int nph = (int)(idx % NPHH);
  long bs = idx / NPHH;
  int s = (int)(bs % SS);
  int h4 = nph * 4;
  float4 acc = *reinterpret_cast<const float4*>(cb + h4);
  uint2 xmr;  // tap w=3 = x_m row bs
#pragma unroll
  for (int w = 0; w < 4; w++) {
    int sp = s + w - 3;
    if (sp < 0) continue;
    uint2 xr = *reinterpret_cast<const uint2*>(xinner + (bs + w - 3) * H2 + h4);
    if (w == 3) xmr = xr;
    const u16* xh = (const u16*)&xr;
    float4 cwv = *reinterpret_cast<const float4*>(cw + w * HH + h4);
    acc.x += b2f(xh[0]) * cwv.x;
    acc.y += b2f(xh[1]) * cwv.y;
    acc.z += b2f(xh[2]) * cwv.z;
    acc.w += b2f(xh[3]) * cwv.w;
  }
  float xaf[4] = {silu_f(acc.x), silu_f(acc.y), silu_f(acc.z), silu_f(acc.w)};
  u16 xa16[4] = {f2b(xaf[0]), f2b(xaf[1]), f2b(xaf[2]), f2b(xaf[3])};
  // re-quantize to bf16 to match the previous two-kernel dataflow exactly
#pragma unroll
  for (int d = 0; d < 4; d++) xaf[d] = b2f(xa16[d]);
  const u16* xm = (const u16*)&xmr;
  float xmf[4];
#pragma unroll
  for (int d = 0; d < 4; d++) xmf[d] = b2f(xm[d]);
  *reinterpret_cast<uint2*>(xca + bs * HH + h4) = *reinterpret_cast<uint2*>(xa16);

  union { uint4 v4[2]; u16 h[16]; } wq, wk, wv;
  const uint4* wqp = reinterpret_cast<const uint4*>(Wqkv + nph * 16);
  const uint4* wkp = reinterpret_cast<const uint4*>(Wqkv + 10752 + nph * 16);
  const uint4* wvp = reinterpret_cast<const uint4*>(Wqkv + 21504 + nph * 16);
  wq.v4[0] = wqp[0]; wq.v4[1] = wqp[1];
  wk.v4[0] = wkp[0]; wk.v4[1] = wkp[1];
  wv.v4[0] = wvp[0]; wv.v4[1] = wvp[1];
  u16 qo[4], ko[4], vo[4];
#pragma unroll
  for (int o = 0; o < 4; o++) {
    float aq = 0.f, ak = 0.f, av = 0.f;
#pragma unroll
    for (int d = 0; d < 4; d++) {
      aq += xaf[d] * b2f(wq.h[d * 4 + o]);
      ak += xaf[d] * b2f(wk.h[d * 4 + o]);
      av += xmf[d] * b2f(wv.h[d * 4 + o]);
    }
    qo[o] = f2b(aq); ko[o] = f2b(ak); vo[o] = f2b(av);
  }
  long ob = bs * HH + h4;
  *reinterpret_cast<uint2*>(q + ob) = *reinterpret_cast<uint2*>(qo);
  *reinterpret_cast<uint2*>(k + ob) = *reinterpret_cast<uint2*>(ko);
  *reinterpret_cast<uint2*>(v + ob) = *reinterpret_cast<uint2*>(vo);
}

// ---------------------------------------------------------------------------
// gate_gemv: G[(seg*4096+row)*24 + seg*8 + j] =
//   sum_c X_seg[row,c] * (j<4 ? W_ig : W_fg)[(seg*2688+c)*4 + (j&3)]
// X_0=q, X_1=k, X_2=v. Weights cached in LDS as bf16 [j][c] (43 KB) so the
// wave reads lane-consecutive 16B (conflict-free). One row per wave per iter,
// 8 f32 accumulators, shuffle-reduce, lane0 writes 8 floats.
// Replaces the 55us masked 12288x24 GEMM with a ~10us reduction.
// ---------------------------------------------------------------------------
__global__ __launch_bounds__(256) void gate_gemv(
    const u16* __restrict__ qb, const u16* __restrict__ kb,
    const u16* __restrict__ vb, const float* __restrict__ Wig,
    const float* __restrict__ Wfg, float* __restrict__ G)
{
  __shared__ u16 wlds[8 * HH];   // [j][c], 43008 B
  int seg = blockIdx.y;
  const u16* X = (seg == 0) ? qb : (seg == 1) ? kb : vb;
  int t = threadIdx.x;
  for (int c = t; c < HH; c += 256) {
    float4 wi = *reinterpret_cast<const float4*>(Wig + ((long)seg * HH + c) * 4);
    float4 wf = *reinterpret_cast<const float4*>(Wfg + ((long)seg * HH + c) * 4);
    wlds[0 * HH + c] = f2b(wi.x); wlds[1 * HH + c] = f2b(wi.y);
    wlds[2 * HH + c] = f2b(wi.z); wlds[3 * HH + c] = f2b(wi.w);
    wlds[4 * HH + c] = f2b(wf.x); wlds[5 * HH + c] = f2b(wf.y);
    wlds[6 * HH + c] = f2b(wf.z); wlds[7 * HH + c] = f2b(wf.w);
  }
  __syncthreads();
  int wv = t >> 6, lane = t & 63;
  int r0 = blockIdx.x * 32 + wv * 8;
  for (int r = 0; r < 8; ++r) {
    int row = r0 + r;
    const u16* xr = X + (long)row * HH;
    float a0=0,a1=0,a2=0,a3=0,a4=0,a5=0,a6=0,a7=0;
    for (int ch = lane; ch < HH / 8; ch += 64) {
      uint4 xv = *reinterpret_cast<const uint4*>(xr + ch * 8);
      const u16* xe = (const u16*)&xv;
      float xf[8];
#pragma unroll
      for (int e = 0; e < 8; ++e) xf[e] = b2f(xe[e]);
#pragma unroll
      for (int j = 0; j < 8; ++j) {
        uint4 wv4 = *reinterpret_cast<const uint4*>(wlds + j * HH + ch * 8);
        const u16* we = (const u16*)&wv4;
        float s = 0.f;
#pragma unroll
        for (int e = 0; e < 8; ++e) s += xf[e] * b2f(we[e]);
        if (j == 0) a0 += s; else if (j == 1) a1 += s;
        else if (j == 2) a2 += s; else if (j == 3) a3 += s;
        else if (j == 4) a4 += s; else if (j == 5) a5 += s;
        else if (j == 6) a6 += s; else a7 += s;
      }
    }
#pragma unroll
    for (int off = 32; off > 0; off >>= 1) {
      a0 += __shfl_down(a0, off); a1 += __shfl_down(a1, off);
      a2 += __shfl_down(a2, off); a3 += __shfl_down(a3, off);
      a4 += __shfl_down(a4, off); a5 += __shfl_down(a5, off);
      a6 += __shfl_down(a6, off); a7 += __shfl_down(a7, off);
    }
    if (lane == 0) {
      float* g = G + ((long)seg * 4096 + row) * 24 + seg * 8;
      g[0] = a0; g[1] = a1; g[2] = a2; g[3] = a3;
      g[4] = a4; g[5] = a5; g[6] = a6; g[7] = a7;
    }
  }
}

// ---------------------------------------------------------------------------
// per (b,n): ipre/fpre from G (12288x24) + bias; cs=cumsum(logsig(f));
// a=i-cs; rmax=prefmax(a); m=cs+rmax
__global__ __launch_bounds__(1024) void scan_kernel(
    const float* __restrict__ G, const float* __restrict__ big,
    const float* __restrict__ bfg,
    float* __restrict__ avec, float* __restrict__ rmaxvec, float* __restrict__ mvec)
{
  __shared__ float buf[2][SS];
  __shared__ float isave[SS];
  __shared__ float cssave[SS];
  int bn = blockIdx.x;
  int b = bn >> 2, n = bn & 3;
  int t = threadIdx.x;
  float bi = big[n], bf = bfg[n];
  for (int i = t; i < SS; i += 1024) {
    long tk = (long)b * SS + i;
    float ip = G[tk * 24 + n] + G[(4096 + tk) * 24 + 8 + n] +
               G[(8192 + tk) * 24 + 16 + n] + bi;
    float fp = G[tk * 24 + 4 + n] + G[(4096 + tk) * 24 + 12 + n] +
               G[(8192 + tk) * 24 + 20 + n] + bf;
    isave[i] = ip;
    buf[0][i] = logsig_f(fp);
  }
  __syncthreads();
  int src = 0;
  for (int off = 1; off < SS; off <<= 1) {
    int dst = 1 - src;
    for (int i = t; i < SS; i += 1024) {
      float x = buf[src][i];
      if (i >= off) x += buf[src][i - off];
      buf[dst][i] = x;
    }
    __syncthreads();
    src = dst;
  }
  for (int i = t; i < SS; i += 1024) {
    float cs = buf[src][i];
    cssave[i] = cs;
    float a = isave[i] - cs;
    avec[(long)bn * SS + i] = a;
    buf[src][i] = a;
  }
  __syncthreads();
  for (int off = 1; off < SS; off <<= 1) {
    int dst = 1 - src;
    for (int i = t; i < SS; i += 1024) {
      float x = buf[src][i];
      if (i >= off) x = fmaxf(x, buf[src][i - off]);
      buf[dst][i] = x;
    }
    __syncthreads();
    src = dst;
  }
  for (int i = t; i < SS; i += 1024) {
    rmaxvec[(long)bn * SS + i] = buf[src][i];
    mvec[(long)bn * SS + i] = cssave[i] + buf[src][i];
  }
}

// ---------------------------------------------------------------------------
// causal row sums of P -> inv_n (vectorized uint4 + in-bounds scalar tail)
__global__ __launch_bounds__(256) void rowsum_kernel(
    const u16* __restrict__ P, const float* __restrict__ mvec, float* __restrict__ invn,
    long Pstride)
{
  int bz = blockIdx.z;
  P += (long)bz * Pstride;
  mvec += (long)bz * SS;
  invn += (long)bz * SS;
  int row = (blockIdx.x * 256 + threadIdx.x) >> 6;
  int lane = threadIdx.x & 63;
  if (row >= SS) return;
  const u16* pr = P + (long)row * SS;
  float s = 0.f;
  int j0 = lane * 8;
  for (; j0 + 7 <= row; j0 += 512) {
    uint4 u = *reinterpret_cast<const uint4*>(pr + j0);
    const u16* e = (const u16*)&u;
#pragma unroll
    for (int q = 0; q < 8; ++q) s += b2f(e[q]);
  }
  if (j0 <= row) {
    for (int q = 0; j0 + q <= row; ++q) s += b2f(pr[j0 + q]);
  }
#pragma unroll
  for (int off = 32; off > 0; off >>= 1) s += __shfl_down(s, off);
  if (lane == 0) {
    float n = fmaxf(fabsf(s), __expf(-mvec[row]));
    invn[row] = 1.f / (n + 1e-6f);
  }
}

// ---------------------------------------------------------------------------
// multi-head layernorm + skip + gate (paired u32 bf16 loads)
__global__ __launch_bounds__(256) void ln_skip_gate(
    const u16* __restrict__ h, const u16* __restrict__ xca,
    const u16* __restrict__ xinner, const float* __restrict__ normw,
    const float* __restrict__ skipw, u16* __restrict__ hs)
{
  int row = (blockIdx.x * 256 + threadIdx.x) >> 6;  // (b*NH+n)*S + s
  int lane = threadIdx.x & 63;
  if (row >= BB * NHH * SS) return;
  int s = row % SS;
  int n = (row / SS) % NHH;
  int b = row / (SS * NHH);
  const u16* hr = h + (long)row * DHH;
  float sum = 0.f, ss = 0.f;
  float vx[6], vy[6];
#pragma unroll
  for (int i = 0; i < 6; ++i) {
    int d2 = lane + i * 64;
    float x = 0.f, y = 0.f;
    if (d2 < DHH / 2) {
      u32 u = *reinterpret_cast<const u32*>(hr + d2 * 2);
      x = b2f((u16)u); y = b2f((u16)(u >> 16));
    }
    vx[i] = x; vy[i] = y;
    sum += x + y; ss += x * x + y * y;
  }
#pragma unroll
  for (int off = 32; off > 0; off >>= 1) { sum += __shfl_down(sum, off); ss += __shfl_down(ss, off); }
  sum = __shfl(sum, 0); ss = __shfl(ss, 0);
  float mu = sum / (float)DHH;
  float var = ss / (float)DHH - mu * mu;
  float rstd = rsqrtf(var + 1e-5f);
  long bs = (long)b * SS + s;
#pragma unroll
  for (int i = 0; i < 6; ++i) {
    int d2 = lane + i * 64;
    if (d2 >= DHH / 2) continue;
    int c = n * DHH + d2 * 2;
    float2 nw = *reinterpret_cast<const float2*>(normw + c);
    float2 sw = *reinterpret_cast<const float2*>(skipw + c);
    u32 xcu = *reinterpret_cast<const u32*>(xca + bs * HH + c);
    u32 zu  = *reinterpret_cast<const u32*>(xinner + bs * H2 + HH + c);
    float h0 = (vx[i] - mu) * rstd * nw.x + sw.x * b2f((u16)xcu);
    float h1 = (vy[i] - mu) * rstd * nw.y + sw.y * b2f((u16)(xcu >> 16));
    float o0 = h0 * silu_f(b2f((u16)zu));
    float o1 = h1 * silu_f(b2f((u16)(zu >> 16)));
    u32 ou = (u32)f2b(o0) | ((u32)f2b(o1) << 16);
    *reinterpret_cast<u32*>(hs + bs * HH + c) = ou;
  }
}

// ---------------------------------------------------------------------------
__global__ __launch_bounds__(256) void fill_sentinel(float* out, float v, long n) {
  long i = (long)blockIdx.x * 256 + threadIdx.x;
  if (i < n) out[i] = v;
}

// ---------------------------------------------------------------------------
extern "C" void kernel_launch(void* const* d_in, const int* in_sizes, int n_in,
                              void* d_out, int out_size, void* d_ws, size_t ws_size,
                              hipStream_t stream)
{
  const float* x      = (const float*)d_in[0];
  const float* W_in   = (const float*)d_in[1];
  const float* conv_w = (const float*)d_in[2];
  const float* conv_b = (const float*)d_in[3];
  const float* Wq     = (const float*)d_in[4];
  const float* Wk     = (const float*)d_in[5];
  const float* Wv     = (const float*)d_in[6];
  const float* W_ig   = (const float*)d_in[7];
  const float* b_ig   = (const float*)d_in[8];
  const float* W_fg   = (const float*)d_in[9];
  const float* b_fg   = (const float*)d_in[10];
  const float* norm_w = (const float*)d_in[11];
  const float* skipw  = (const float*)d_in[12];
  const float* W_out  = (const float*)d_in[13];
  float* out = (float*)d_out;
  const long SD = (long)SS * DHH;     // head slice elems
  const long SP = (long)SS * SS;
  const long BH = (long)SS * HH;      // per-batch elems of (S,H)

  u16* ws = (u16*)d_ws;
  size_t off = 0;
  auto alloc = [&](size_t n) { u16* p = ws + off; off += n; return p; };
  u16* x_inner = alloc((size_t)4096 * H2);
  u16* xca     = alloc((size_t)4096 * HH);
  u16* qb      = alloc((size_t)4096 * HH);   // W_inT -> q -> hs
  u16* kb      = alloc((size_t)4096 * HH);   // xbf -> k -> h
  u16* vb      = alloc((size_t)4096 * HH);   // v -> W_outT
  float* fvec  = (float*)(ws + off);
  off += 4 * 16384 * 2;
  float* avec    = fvec;
  float* rmaxvec = avec + 16384;
  float* mvec    = rmaxvec + 16384;
  float* invn    = mvec + 16384;
  u16* vt8 = alloc((size_t)8 * SD);
  u16* Pb8 = alloc((size_t)8 * SP);
  size_t need = off * 2;
  long outn = (long)4096 * EE;

  if (ws_size < need) {
    fill_sentinel<<<dim3((outn + 255) / 256), 256, 0, stream>>>(
        out, 200.f + 0.01f * (float)(ws_size >> 20), outn);
    return;
  }

  // overlays
  u16* W_inT  = qb;                       // consumed before conv_head writes q
  u16* xbf    = kb;                       // consumed before conv_head writes k
  u16* W_outT = vb;                       // written after v's last use
  u16* hbuf   = kb;                       // h (bn,S,DH) after k's last use
  u16* hsbuf  = qb;                       // hs after q's last use
  float* G    = (float*)(Pb8 + 344064);   // 12288x24 fp32, consumed before QK
  u16* Wqkv   = Pb8 + 933888;             // 3x10752, consumed before QK

  prep_wqkv<<<dim3(126, 1, 1), 256, 0, stream>>>(Wq, Wk, Wv, Wqkv);
  transpose_any<1><<<dim3(84, 32, 1), 256, 0, stream>>>(
      W_in, W_inT, EE, H2, H2, 0, 0, 0);
  convert_x<<<dim3(4096, 1, 1), 256, 0, stream>>>(x, xbf);
  // x_inner = x @ W_in : M=4096 N=5376 K=2048 (128x256 tiles, 672 blocks)
  gemm8<0, 0><<<dim3(21, 32, 1), 512, 0, stream>>>(
      xbf, W_inT, x_inner, 4096, H2, EE, EE, EE, H2,
      0, 0, 0, 0, 0, 0, nullptr, nullptr, 0, 0);
  // fused conv+silu+headwise: writes xca, q, k, v
  conv_head<<<dim3(10752, 1, 1), 256, 0, stream>>>(
      x_inner, conv_w, conv_b, Wqkv, xca, qb, kb, vb);
  // gates as a GEMV-reduction (replaces the 12288x24 masked GEMM)
  gate_gemv<<<dim3(128, 3, 1), 256, 0, stream>>>(qb, kb, vb, W_ig, W_fg, G);
  scan_kernel<<<dim3(8, 1, 1), 1024, 0, stream>>>(G, b_ig, b_fg, avec, rmaxvec, mvec);
  // v^T per (b,n): (DH, S)
  transpose_any<0><<<dim3(11, 32, 8), 256, 0, stream>>>(
      vb, vt8, SS, DHH, HH, BH, DHH, SD);
  // P = (q k^T / sqrt(DH)) * exp(a[col]-rmax[row]), causal; K=672 -> BK32 path
  gemm_p<256, 1, 0><<<dim3(8, 8, 8), 512, 0, stream>>>(
      qb, kb, Pb8, SS, SS, DHH, HH, HH, SS,
      BH, DHH, BH, DHH, 4 * SP, SP, avec, rmaxvec, SS, 0);
  rowsum_kernel<<<dim3(512, 1, 8), 256, 0, stream>>>(Pb8, mvec, invn, SP);
  // h = (P @ v) * inv_n, into (bn, S, DH); Keff = m0+128 (mult of 64 ok);
  // B over-reads vt8 rows 672..767 (in-bounds garbage, masked by col<N)
  gemm8<2, 0><<<dim3(3, 16, 8), 512, 0, stream>>>(
      Pb8, vt8, hbuf, SS, DHH, SS, SS, SS, DHH,
      4 * SP, SP, 4 * SD, SD, 4 * SD, SD, invn, nullptr, SS, 1);
  transpose_any<1><<<dim3(32, 42, 1), 256, 0, stream>>>(
      W_out, W_outT, HH, EE, EE, 0, 0, 0);
  ln_skip_gate<<<dim3(4096, 1, 1), 256, 0, stream>>>(
      hbuf, xca, x_inner, norm_w, skipw, hsbuf);
  gemm8<0, 1><<<dim3(8, 32, 1), 512, 0, stream>>>(
      hsbuf, W_outT, out, 4096, EE, HH, HH, HH, EE,
      0, 0, 0, 0, 0, 0, nullptr, nullptr, 0, 0);
}